// Round 10
// baseline (1854.962 us; speedup 1.0000x reference)
//
#include <hip/hip_runtime.h>
#include <hip/hip_fp16.h>

typedef _Float16 f16;
typedef __attribute__((ext_vector_type(8))) _Float16 f16x8;
typedef __attribute__((ext_vector_type(4))) _Float16 f16x4;
typedef __attribute__((ext_vector_type(4))) float f32x4;

#define D_      512
#define NG_     2048
#define B_      64
#define S_      256
#define C_      16
#define M_      (B_*S_)      // 16384

// ---- workspace layout (bytes) ----
#define OFF_X    0ull
#define SZ_X     ((unsigned long long)M_*D_*2)            // x fp16 [16384][512]
#define OFF_G    (OFF_X + SZ_X)
#define SZ_G     ((unsigned long long)M_*NG_*2)           // G2 fp16 [16384][512][4] gate-interleaved
#define OFF_WI   (OFF_G + SZ_G)
#define SZ_WI    ((unsigned long long)NG_*D_*2)           // W_ih fp16
#define OFF_SL   (OFF_WI + SZ_WI)
#define SZ_SL    (2ull*4*16*256*8)                        // slab dbl-buf [2][4cl][16ch][256 slot] u64
#define OFF_FH   (OFF_SL + SZ_SL)
#define SZ_FH    ((unsigned long long)B_*D_*4)            // final_h f32 [64][512]
#define WS_NEED  (OFF_FH + SZ_FH)

__device__ __forceinline__ float sigmoidf_(float x) { return 1.f / (1.f + __expf(-x)); }
__device__ __forceinline__ float tanhf_(float x) {
  float a = fabsf(x);
  float e = __expf(-2.f * a);
  float r = (1.f - e) / (1.f + e);
  return copysignf(r, x);
}

// ---------------- K1: embedding gather + sum -> x fp16 ----------------
__global__ void k_embed(const int* __restrict__ seqs, const float* __restrict__ table,
                        f16* __restrict__ x) {
  const int m = blockIdx.x;
  const int t = threadIdx.x;
  const int* idx = seqs + (size_t)m * C_;
  float4 acc = {0.f, 0.f, 0.f, 0.f};
  #pragma unroll
  for (int r = 0; r < C_; ++r) {
    int id = idx[r];  // row VOCAB is all-zero in the provided table
    const float4* row = (const float4*)(table + (size_t)id * D_);
    float4 v = row[t];
    acc.x += v.x; acc.y += v.y; acc.z += v.z; acc.w += v.w;
  }
  f16x4 o;
  o[0] = (f16)acc.x; o[1] = (f16)acc.y; o[2] = (f16)acc.z; o[3] = (f16)acc.w;
  *(f16x4*)(x + (size_t)m * D_ + t * 4) = o;
}

// ---------------- K1b: convert W_ih fp32 -> fp16 ----------------
__global__ void k_cvtw(const float* __restrict__ w, f16* __restrict__ o, int n) {
  int i = blockIdx.x * 256 + threadIdx.x;
  if (i < n) o[i] = (f16)w[i];
}

// ---------------- K2: G2 = x @ W_ih^T, gate-interleaved output ----------------
// grid (32 ntiles, 256 mtiles) x 256 thr. Output: G2[m][col][gate].
__global__ void k_gemm_ih(const f16* __restrict__ x, const f16* __restrict__ wi,
                          f16* __restrict__ G2) {
  const int nt = blockIdx.x, mt = blockIdx.y;
  const int wid = threadIdx.x >> 6, lane = threadIdx.x & 63;
  const int lr = lane & 15, lq = lane >> 4;
  const int m0 = mt * 64 + wid * 16;
  const int n0 = nt * 64;
  const int gate = nt >> 3;
  const int cbase = (nt & 7) * 64;  // within-gate col base

  f32x4 acc[4] = {{0.f,0.f,0.f,0.f},{0.f,0.f,0.f,0.f},{0.f,0.f,0.f,0.f},{0.f,0.f,0.f,0.f}};
  for (int kt = 0; kt < 16; ++kt) {
    const int k0 = kt * 32 + lq * 8;
    const f16x8 a = *(const f16x8*)(x + (size_t)(m0 + lr) * D_ + k0);
    #pragma unroll
    for (int j = 0; j < 4; ++j) {
      const f16x8 b = *(const f16x8*)(wi + (size_t)(n0 + j * 16 + lr) * D_ + k0);
      acc[j] = __builtin_amdgcn_mfma_f32_16x16x32_f16(a, b, acc[j], 0, 0, 0);
    }
  }
  // D mapping: col = lane&15 (n), row = (lane>>4)*4 + reg (m)
  #pragma unroll
  for (int j = 0; j < 4; ++j)
    #pragma unroll
    for (int rr = 0; rr < 4; ++rr) {
      const int m = m0 + lq * 4 + rr;
      const int col = cbase + j * 16 + lr;
      G2[(size_t)m * NG_ + col * 4 + gate] = (f16)acc[j][rr];
    }
}

// ---------------- K3: LSTM recurrence ----------------
// 64 WGs x 512 thr. cluster cl = bid&3 (16 WGs, 16 chains); rank r = bid>>2.
// WG owns 128 W_hh rows as persistent VGPR B-frags (64 VGPR, no spill).
// EXCHANGE: NO flags. Each slab slot is a self-validating 8B atomic
// {seq=t+1 (hi32) | 2xf16 h-pair (lo32)}. Producer: one relaxed agent dwordx2
// store. Consumer: polls its own 8 slots until all carry seq t+1, s_sleep(1)
// backoff, BOUNDED (guard breaks after 64K rounds -> wrong answer, not a hang;
// R8's cross-cluster slot aliasing hung the container: equality-poll on a slot
// owned by an unsynchronized foreign cluster never matched).
// SLOT MAP (bijective): qword = buf*16384 + cl*4096 + chain*256 + r*16 + (ej>>1).
// Consumer (gc,gq) reads slots [gq*8,gq*8+8) of chain gc (producer r = gq>>1);
// barrier B makes every WG wait on the whole cluster each step.
// Dbl-buf safety: producer reaches step t+2 overwrite of buf t&1 only after its
// step t+1 poll saw seq t+2 from ALL 16 cluster WGs; each publishes seq t+2 only
// after its step-t gather of buf t&1. Poison 0xAAAAAAAA != any seq in [1,256].
__global__ __launch_bounds__(512, 1) void k_lstm(
    const float* __restrict__ whh, const f16* __restrict__ G2,
    const int* __restrict__ lengths, unsigned long long* __restrict__ slab,
    float* __restrict__ final_h) {
  const int bid = blockIdx.x;
  const int cl = bid & 3;
  const int r = bid >> 2;          // 0..15
  const int tid = threadIdx.x;
  const int wid = tid >> 6, lane = tid & 63;
  const int lr = lane & 15, lq = lane >> 4;

  __shared__ f16 h_lds[16][522];     // 261 dwords/row; 261%32=5 -> banks spread
  __shared__ float glds[4][32][21];  // [gate][h-col in WG][chain], odd pad
  __shared__ int steps_sh;

  // persistent W_hh B-frags: wave wid -> gate (wid>>1), half (wid&1); 16 x f16x8
  const int gi = wid >> 1, jh = wid & 1;
  const int nrow = gi * 512 + r * 32 + jh * 16 + lr;
  f16x8 wfrag[16];
  #pragma unroll
  for (int kt = 0; kt < 16; ++kt) {
    const int k0 = kt * 32 + lq * 8;
    const float* p = whh + (size_t)nrow * D_ + k0;
    f16x8 w;
    #pragma unroll
    for (int e = 0; e < 8; ++e) w[e] = (f16)p[e];
    wfrag[kt] = w;
  }

  for (int i = tid; i < 16 * 522; i += 512) ((f16*)h_lds)[i] = (f16)0.f;

  // epilogue mapping: chain ec = tid>>5, h-col ej = tid&31
  const int ec = tid >> 5;
  const int ej = tid & 31;
  const int b_ec = cl * 16 + ec;
  const int len_ec = lengths[b_ec];

  if (tid == 0) {
    int mx = 0;
    for (int c = 0; c < 16; ++c) mx = max(mx, lengths[cl * 16 + c]);
    steps_sh = mx;
  }
  float cstate = 0.f;
  __syncthreads();
  const int steps = steps_sh;

  // gather mapping: chain gc = tid&15, slot-group gq = tid>>4 (8 slots = 16 f16)
  const int gc = tid & 15;
  const int gq = tid >> 4;

  // G fragment prefetch (t = 0)
  const size_t gb = (size_t)b_ec * S_ * NG_ + (size_t)(r * 32 + ej) * 4;
  f16x4 gf = *(const f16x4*)(G2 + gb);

  // slab qword indices: [buf*16384 + cl*4096 + chain*256 + slot]
  const size_t prod_slot = (size_t)cl * 4096 + ec * 256 + r * 16 + (ej >> 1);
  const size_t cons_base = (size_t)cl * 4096 + gc * 256 + gq * 8;

  for (int t = 0; t < steps; ++t) {
    // 1. MFMA: two independent 8-deep chains (halved dependent latency)
    f32x4 a0 = {0.f, 0.f, 0.f, 0.f}, a1 = {0.f, 0.f, 0.f, 0.f};
    #pragma unroll
    for (int kt = 0; kt < 8; ++kt) {
      const f16x8 ha = *(const f16x8*)&h_lds[lr][kt * 32 + lq * 8];
      const f16x8 hb = *(const f16x8*)&h_lds[lr][(kt + 8) * 32 + lq * 8];
      a0 = __builtin_amdgcn_mfma_f32_16x16x32_f16(ha, wfrag[kt], a0, 0, 0, 0);
      a1 = __builtin_amdgcn_mfma_f32_16x16x32_f16(hb, wfrag[kt + 8], a1, 0, 0, 0);
    }
    #pragma unroll
    for (int rr = 0; rr < 4; ++rr)
      glds[gi][jh * 16 + lr][lq * 4 + rr] = a0[rr] + a1[rr];
    __syncthreads();  // barrier A: glds ready; h_lds reads done

    // 2. epilogue: thread (ec, ej)
    {
      float ig = glds[0][ej][ec] + (float)gf[0];
      float fg = glds[1][ej][ec] + (float)gf[1];
      float gg = glds[2][ej][ec] + (float)gf[2];
      float og = glds[3][ej][ec] + (float)gf[3];
      ig = sigmoidf_(ig); fg = sigmoidf_(fg); og = sigmoidf_(og); gg = tanhf_(gg);
      cstate = fg * cstate + ig * gg;
      const float hv = og * tanhf_(cstate);
      if (t == len_ec - 1) final_h[(size_t)b_ec * D_ + r * 32 + ej] = hv;

      // self-validating slab store: {seq | h-pair}, one 8B relaxed agent atomic
      unsigned hb2 = (unsigned)(unsigned short)__builtin_bit_cast(unsigned short, (f16)hv);
      unsigned other = __shfl_xor(hb2, 1);
      if (!(ej & 1)) {
        const unsigned long long pv =
            ((unsigned long long)(unsigned)(t + 1) << 32) | (hb2 | (other << 16));
        __hip_atomic_store(&slab[(size_t)(t & 1) * 16384 + prod_slot], pv,
                           __ATOMIC_RELAXED, __HIP_MEMORY_SCOPE_AGENT);
      }
    }

    // 3. prefetch next-step G (drains at barrier B under poll/gather cover)
    {
      const int tn = min(t + 1, S_ - 1);
      gf = *(const f16x4*)(G2 + gb + (size_t)tn * NG_);
    }

    // 4. bounded poll of own 8 slots until all carry seq t+1, then write h_lds
    {
      const unsigned long long* src = slab + (size_t)(t & 1) * 16384 + cons_base;
      unsigned long long v[8];
      const unsigned want = (unsigned)(t + 1);
      unsigned guard = 0;
      for (;;) {
        #pragma unroll
        for (int e = 0; e < 8; ++e)
          v[e] = __hip_atomic_load(&src[e], __ATOMIC_RELAXED, __HIP_MEMORY_SCOPE_AGENT);
        bool ok = true;
        #pragma unroll
        for (int e = 0; e < 8; ++e) ok &= ((unsigned)(v[e] >> 32) == want);
        if (__all(ok)) break;
        if (++guard > 65536u) break;   // hang guard: fail visibly, don't wedge
        __builtin_amdgcn_s_sleep(1);
      }
      unsigned* dst = (unsigned*)&h_lds[gc][gq * 16];
      #pragma unroll
      for (int e = 0; e < 8; ++e) dst[e] = (unsigned)v[e];
    }
    __syncthreads();  // barrier B: h(t+1) in LDS; drains slab stores + gf
  }
}

// ---------------- K4: out = final_h @ w_out^T + b_out ----------------
__global__ void k_head(const float* __restrict__ fh, const float* __restrict__ wout,
                       const float* __restrict__ bout, float* __restrict__ out) {
  const int b = blockIdx.x;
  const int lane = threadIdx.x;  // 64
  float p0 = 0.f, p1 = 0.f;
  for (int k = lane; k < D_; k += 64) {
    const float h = fh[(size_t)b * D_ + k];
    p0 += h * wout[k];
    p1 += h * wout[D_ + k];
  }
  #pragma unroll
  for (int off = 32; off; off >>= 1) {
    p0 += __shfl_down(p0, off);
    p1 += __shfl_down(p1, off);
  }
  if (lane == 0) {
    out[b * 2 + 0] = p0 + bout[0];
    out[b * 2 + 1] = p1 + bout[1];
  }
}

extern "C" void kernel_launch(void* const* d_in, const int* in_sizes, int n_in,
                              void* d_out, int out_size, void* d_ws, size_t ws_size,
                              hipStream_t stream) {
  const int* seqs = (const int*)d_in[0];
  const int* lengths = (const int*)d_in[1];
  const float* table = (const float*)d_in[2];
  const float* wih = (const float*)d_in[3];
  const float* whh = (const float*)d_in[4];
  const float* wout = (const float*)d_in[5];
  const float* bout = (const float*)d_in[6];
  float* out = (float*)d_out;
  char* ws = (char*)d_ws;
  if (ws_size < WS_NEED) return;

  f16* x = (f16*)(ws + OFF_X);
  f16* G2 = (f16*)(ws + OFF_G);
  f16* wi16 = (f16*)(ws + OFF_WI);
  unsigned long long* slab = (unsigned long long*)(ws + OFF_SL);
  float* fh = (float*)(ws + OFF_FH);

  hipLaunchKernelGGL(k_embed, dim3(M_), dim3(128), 0, stream, seqs, table, x);
  hipLaunchKernelGGL(k_cvtw, dim3((NG_ * D_ + 255) / 256), dim3(256), 0, stream,
                     wih, wi16, NG_ * D_);
  hipLaunchKernelGGL(k_gemm_ih, dim3(NG_ / 64, M_ / 64), dim3(256), 0, stream, x, wi16, G2);
  hipLaunchKernelGGL(k_lstm, dim3(64), dim3(512), 0, stream, whh, G2, lengths, slab, fh);
  hipLaunchKernelGGL(k_head, dim3(B_), dim3(64), 0, stream, fh, wout, bout, out);
}